// Round 2
// baseline (552.036 us; speedup 1.0000x reference)
//
#include <hip/hip_runtime.h>
#include <cstdint>

// ---------------------------------------------------------------------------
// WindowAttention (Swin): B_WIN=4096 windows, N=49 tokens, DIM=256, HEADS=8,
// head_dim=32, NW=64 masks.
// Pipeline: cvt_w -> comb -> qkv gemm (fp32-A fused cvt, swizzled LDS, XCD
// mapping) -> fused attention+proj (shuffle softmax, proj in-block).
// ---------------------------------------------------------------------------

typedef __attribute__((ext_vector_type(8))) short short8;   // bf16x8 frag
typedef __attribute__((ext_vector_type(4))) float floatx4;  // fp32x4 acc frag

__device__ __forceinline__ ushort f2bf(float f) {
    uint32_t u = __float_as_uint(f);
    u += 0x7FFFu + ((u >> 16) & 1u);   // RNE
    return (ushort)(u >> 16);
}

__device__ __forceinline__ uint32_t cvtpk(float lo, float hi) {
    uint32_t r;
    asm("v_cvt_pk_bf16_f32 %0, %1, %2" : "=v"(r) : "v"(lo), "v"(hi));
    return r;
}

__device__ __forceinline__ void gl_lds16(const void* g, void* lds) {
    __builtin_amdgcn_global_load_lds(
        (const __attribute__((address_space(1))) uint32_t*)g,
        (__attribute__((address_space(3))) uint32_t*)lds, 16, 0, 0);
}

// ---------------------------------------------------------------- kernel 0b
__global__ __launch_bounds__(256) void k_cvt_w(const float* __restrict__ qw,
                                               const float* __restrict__ pw,
                                               ushort* __restrict__ qwb,
                                               ushort* __restrict__ pwb) {
    int i = blockIdx.x * 256 + threadIdx.x;
    if (i < 196608) qwb[i] = f2bf(qw[i]);
    else            pwb[i - 196608] = f2bf(pw[i - 196608]);
}

// ---------------------------------------------------------------- kernel 0c
// comb[w][h][n][m] = mask[w][n][m] + bias_table[rel_index[n][m]][h]
__global__ __launch_bounds__(256) void k_comb(const float* __restrict__ mask,
                                              const int* __restrict__ rel,
                                              const float* __restrict__ bt,
                                              float* __restrict__ comb) {
    const int wh = blockIdx.x;
    const int w = wh >> 3, h = wh & 7;
    const float* mw = mask + (size_t)w * 2401;
    float* out = comb + (size_t)wh * 2401;
    for (int e = threadIdx.x; e < 2401; e += 256)
        out[e] = mw[e] + bt[rel[e] * 8 + h];
}

// ---------------------------------------------------------------- kernel 1
// qkv gemm: C[tok][c] = sum_k x[tok][k]*qkv_w[c][k] + qkv_b[c]
// A read fp32 straight from x (convert on frag read). M=200704, N=768, K=256.
// BM=BN=128, BK=32. LDS XOR-swizzled (A: chunk^=(row&7) of 8x16B chunks;
// B: chunk^=((row>>1)&3) of 4x16B chunks) -> 2-way max (free).
// XCD-contiguous mapping: blocks sharing an A-tile land on one XCD.
__global__ __launch_bounds__(256) void k_qkv(const float* __restrict__ x,
                                             const ushort* __restrict__ wb,
                                             const float* __restrict__ qb,
                                             ushort* __restrict__ qws,
                                             ushort* __restrict__ kws,
                                             ushort* __restrict__ vws) {
    __shared__ float  As[128 * 32];   // 16 KB (swizzled chunk layout)
    __shared__ ushort Bs[128 * 32];   // 8 KB  (swizzled chunk layout)
    const int bid = blockIdx.x;
    const int gid = (bid & 7) * 1176 + (bid >> 3);   // bijective, 9408 = 8*1176
    const int bn = gid % 6, bm = gid / 6;            // 1176 % 6 == 0: no split
    const int t = threadIdx.x;
    const int l = t & 63, w = t >> 6;
    const int wm = w >> 1, wn = w & 1;
    const int g = l >> 4;

    const float*  Ag = x  + (size_t)bm * 128 * 256;
    const ushort* Bg = wb + (size_t)bn * 128 * 256;

    const floatx4 zf = {0.f, 0.f, 0.f, 0.f};
    floatx4 acc[4][4];
#pragma unroll
    for (int i = 0; i < 4; ++i)
#pragma unroll
        for (int j = 0; j < 4; ++j) acc[i][j] = zf;

    // staging source columns (pre-swizzled so linear LDS dest = swizzled data)
    const int acol = ((l & 7) ^ (l >> 3)) * 4;         // floats
    const int bcol = ((l & 3) ^ ((l >> 3) & 3)) * 8;   // bf16 elems
    const int arow0 = wm * 64 + (l & 15);
    const int brow0 = wn * 64 + (l & 15);

    char* Asb = (char*)As;
    char* Bsb = (char*)Bs;

    for (int kt = 0; kt < 8; ++kt) {
#pragma unroll
        for (int i = 0; i < 4; ++i)
            gl_lds16(Ag + (size_t)(i * 32 + w * 8 + (l >> 3)) * 256 + kt * 32 + acol,
                     Asb + i * 4096 + w * 1024);
#pragma unroll
        for (int i = 0; i < 2; ++i)
            gl_lds16(Bg + (size_t)(i * 64 + w * 16 + (l >> 2)) * 256 + kt * 32 + bcol,
                     Bsb + i * 4096 + w * 1024);
        __syncthreads();
        short8 af[4], bfr[4];
#pragma unroll
        for (int mt = 0; mt < 4; ++mt) {
            const int row = arow0 + mt * 16;
            const float4 fA = *(const float4*)(Asb + row * 128 + (((2 * g)     ^ (row & 7)) << 4));
            const float4 fB = *(const float4*)(Asb + row * 128 + (((2 * g + 1) ^ (row & 7)) << 4));
            union { short8 s; uint32_t u[4]; } cv;
            cv.u[0] = cvtpk(fA.x, fA.y);
            cv.u[1] = cvtpk(fA.z, fA.w);
            cv.u[2] = cvtpk(fB.x, fB.y);
            cv.u[3] = cvtpk(fB.z, fB.w);
            af[mt] = cv.s;
        }
#pragma unroll
        for (int nt = 0; nt < 4; ++nt) {
            const int row = brow0 + nt * 16;
            bfr[nt] = *(const short8*)(Bsb + row * 64 + ((g ^ ((row >> 1) & 3)) << 4));
        }
#pragma unroll
        for (int mt = 0; mt < 4; ++mt)
#pragma unroll
            for (int nt = 0; nt < 4; ++nt)
                acc[mt][nt] = __builtin_amdgcn_mfma_f32_16x16x32_bf16(
                    af[mt], bfr[nt], acc[mt][nt], 0, 0, 0);
        __syncthreads();
    }

#pragma unroll
    for (int nt = 0; nt < 4; ++nt) {
        const int c = bn * 128 + wn * 64 + nt * 16 + (l & 15);
        const int which = c >> 8, hd = (c >> 5) & 7, dd = c & 31;
        const float bias = qb[c];
        ushort* dst = which == 0 ? qws : (which == 1 ? kws : vws);
#pragma unroll
        for (int mt = 0; mt < 4; ++mt)
#pragma unroll
            for (int r = 0; r < 4; ++r) {
                const int tok = bm * 128 + wm * 64 + mt * 16 + (l >> 4) * 4 + r;
                const int b = tok / 49;
                const int n = tok - b * 49;
                dst[(size_t)(b * 8 + hd) * 1568 + n * 32 + dd] =
                    f2bf(acc[mt][nt][r] + bias);
            }
    }
}

// ---------------------------------------------------------------- kernel 2
// Fused attention + output projection. One block (512 thr, 8 waves) per
// window; wave w = head w. Per-wave LDS: P[64][72] bf16 + vT[32][72] bf16
// (13824 B). After PV the per-wave scratch is dead; ao[64][264] bf16 aliases
// the front of it (barrier-protected). Total LDS = 110592 B.
__global__ __launch_bounds__(512) void k_attn_proj(
        const ushort* __restrict__ qws, const ushort* __restrict__ kws,
        const ushort* __restrict__ vws, const float* __restrict__ comb,
        const ushort* __restrict__ pwb, const float* __restrict__ pb,
        float* __restrict__ out) {
    __shared__ __align__(16) char smem[8 * 13824];   // 110592 B
    const int w = threadIdx.x >> 6;      // wave id == head
    const int l = threadIdx.x & 63;
    const int b = blockIdx.x;
    const int bh = b * 8 + w;
    const int wdw = b & 63;
    const int gq = l >> 4, li = l & 15;

    ushort* P  = (ushort*)(smem + w * 13824);          // [64][72]
    ushort* vT = (ushort*)(smem + w * 13824 + 9216);   // [32][72]
    ushort* ao = (ushort*)smem;                        // [64][264] (aliased)

    const ushort* qg = qws + (size_t)bh * 1568;
    const ushort* kg = kws + (size_t)bh * 1568;
    const ushort* vg = vws + (size_t)bh * 1568;

    // --- Q/K fragments straight from global (each 16B/lane covers 1KB) ---
    const int kq = gq * 8;
    const short8 z8 = {0, 0, 0, 0, 0, 0, 0, 0};
    short8 qf[4], kf[4];
#pragma unroll
    for (int mt = 0; mt < 4; ++mt) {
        const int n = mt * 16 + li;
        qf[mt] = (n < 49) ? *(const short8*)(qg + n * 32 + kq) : z8;
        kf[mt] = (n < 49) ? *(const short8*)(kg + n * 32 + kq) : z8;
    }

    // --- stage V transposed into LDS: vT[dd][m] ---
    uint4 vv[4];
    if (l < 49) {
#pragma unroll
        for (int i = 0; i < 4; ++i) vv[i] = *(const uint4*)(vg + (size_t)l * 32 + i * 8);
    } else {
#pragma unroll
        for (int i = 0; i < 4; ++i) vv[i] = make_uint4(0u, 0u, 0u, 0u);
    }
#pragma unroll
    for (int i = 0; i < 4; ++i) {
        const uint32_t uu[4] = {vv[i].x, vv[i].y, vv[i].z, vv[i].w};
#pragma unroll
        for (int j = 0; j < 4; ++j) {
            const int dd = i * 8 + j * 2;
            vT[dd * 72 + l]       = (ushort)(uu[j] & 0xFFFFu);
            vT[(dd + 1) * 72 + l] = (ushort)(uu[j] >> 16);
        }
    }

    // --- S = scale * Q K^T + comb (in registers) ---
    const floatx4 zf = {0.f, 0.f, 0.f, 0.f};
    floatx4 sac[4][4];
#pragma unroll
    for (int mt = 0; mt < 4; ++mt)
#pragma unroll
        for (int nt = 0; nt < 4; ++nt)
            sac[mt][nt] = __builtin_amdgcn_mfma_f32_16x16x32_bf16(qf[mt], kf[nt], zf, 0, 0, 0);

    const float* cw = comb + (size_t)(wdw * 8 + w) * 2401;
    const float scale = 0.17677669529663687f;  // 32^-0.5
#pragma unroll
    for (int mt = 0; mt < 4; ++mt)
#pragma unroll
        for (int nt = 0; nt < 4; ++nt) {
            const int m = nt * 16 + li;
#pragma unroll
            for (int r = 0; r < 4; ++r) {
                const int n = mt * 16 + gq * 4 + r;
                float v = -1e30f;
                if (m < 49 && n < 49) v = sac[mt][nt][r] * scale + cw[n * 49 + m];
                sac[mt][nt][r] = v;
            }
        }

    // --- shuffle-reduce softmax: row n lives on lanes differing in low 4 bits
    float rs[4][4];
#pragma unroll
    for (int mt = 0; mt < 4; ++mt)
#pragma unroll
        for (int r = 0; r < 4; ++r) {
            float mx = fmaxf(fmaxf(sac[mt][0][r], sac[mt][1][r]),
                             fmaxf(sac[mt][2][r], sac[mt][3][r]));
            mx = fmaxf(mx, __shfl_xor(mx, 1, 64));
            mx = fmaxf(mx, __shfl_xor(mx, 2, 64));
            mx = fmaxf(mx, __shfl_xor(mx, 4, 64));
            mx = fmaxf(mx, __shfl_xor(mx, 8, 64));
            float s = 0.f;
#pragma unroll
            for (int nt = 0; nt < 4; ++nt) {
                const float e = __expf(sac[mt][nt][r] - mx);
                sac[mt][nt][r] = e;
                s += e;
            }
            s += __shfl_xor(s, 1, 64);
            s += __shfl_xor(s, 2, 64);
            s += __shfl_xor(s, 4, 64);
            s += __shfl_xor(s, 8, 64);
            rs[mt][r] = 1.f / s;
        }

    // --- write P (un-normalized bf16), transposed into PV A-operand layout
#pragma unroll
    for (int mt = 0; mt < 4; ++mt)
#pragma unroll
        for (int nt = 0; nt < 4; ++nt) {
            const int m = nt * 16 + li;
#pragma unroll
            for (int r = 0; r < 4; ++r) {
                const int n = mt * 16 + gq * 4 + r;
                P[n * 72 + m] = f2bf(sac[mt][nt][r]);
            }
        }

    // --- O = P V ---
    floatx4 oac[4][2];
#pragma unroll
    for (int mt = 0; mt < 4; ++mt)
#pragma unroll
        for (int nt = 0; nt < 2; ++nt) oac[mt][nt] = zf;
#pragma unroll
    for (int ks = 0; ks < 2; ++ks) {
        short8 vf[2];
#pragma unroll
        for (int nt = 0; nt < 2; ++nt) {
            const int dd = nt * 16 + li;
            vf[nt] = *(const short8*)(vT + dd * 72 + ks * 32 + gq * 8);
        }
#pragma unroll
        for (int mt = 0; mt < 4; ++mt) {
            const int n = mt * 16 + li;
            const short8 pf = *(const short8*)(P + n * 72 + ks * 32 + gq * 8);
#pragma unroll
            for (int nt = 0; nt < 2; ++nt)
                oac[mt][nt] = __builtin_amdgcn_mfma_f32_16x16x32_bf16(pf, vf[nt], oac[mt][nt], 0, 0, 0);
        }
    }

    __syncthreads();   // all waves done with P/vT; safe to alias with ao

    // --- normalize + store O into ao[n][h*32+dd]; zero-pad rows 49..63 ---
#pragma unroll
    for (int mt = 0; mt < 4; ++mt)
#pragma unroll
        for (int rr = 0; rr < 4; ++rr) {
            const int n = mt * 16 + gq * 4 + rr;
            if (n < 49) {
                const float r1 = rs[mt][rr];
#pragma unroll
                for (int nt = 0; nt < 2; ++nt) {
                    const int dd = nt * 16 + li;
                    ao[n * 264 + w * 32 + dd] = f2bf(oac[mt][nt][rr] * r1);
                }
            }
        }
    for (int idx = l; idx < 15 * 16; idx += 64) {
        const int n = 49 + (idx >> 4);
        const int du = idx & 15;
        *(uint32_t*)(ao + n * 264 + w * 32 + du * 2) = 0u;
    }
    __syncthreads();

    // --- proj: out[n][c] = sum_k ao[n][k] * proj_w[c][k] + proj_b[c] ---
    // wave w covers cols [w*32, w*32+32)
    floatx4 pacc[4][2];
#pragma unroll
    for (int mt = 0; mt < 4; ++mt)
#pragma unroll
        for (int nt = 0; nt < 2; ++nt) pacc[mt][nt] = zf;
#pragma unroll
    for (int kt = 0; kt < 8; ++kt) {
        short8 afr[4], wfr[2];
#pragma unroll
        for (int mt = 0; mt < 4; ++mt)
            afr[mt] = *(const short8*)(ao + (mt * 16 + li) * 264 + kt * 32 + gq * 8);
#pragma unroll
        for (int nt = 0; nt < 2; ++nt)
            wfr[nt] = *(const short8*)(pwb + (size_t)(w * 32 + nt * 16 + li) * 256 + kt * 32 + gq * 8);
#pragma unroll
        for (int mt = 0; mt < 4; ++mt)
#pragma unroll
            for (int nt = 0; nt < 2; ++nt)
                pacc[mt][nt] = __builtin_amdgcn_mfma_f32_16x16x32_bf16(
                    afr[mt], wfr[nt], pacc[mt][nt], 0, 0, 0);
    }

    float* og = out + (size_t)b * 49 * 256;
#pragma unroll
    for (int nt = 0; nt < 2; ++nt) {
        const int c = w * 32 + nt * 16 + li;
        const float bias = pb[c];
#pragma unroll
        for (int mt = 0; mt < 4; ++mt)
#pragma unroll
            for (int r = 0; r < 4; ++r) {
                const int n = mt * 16 + gq * 4 + r;
                if (n < 49) og[(size_t)n * 256 + c] = pacc[mt][nt][r] + bias;
            }
    }
}

// ---------------------------------------------------------------------------
extern "C" void kernel_launch(void* const* d_in, const int* in_sizes, int n_in,
                              void* d_out, int out_size, void* d_ws, size_t ws_size,
                              hipStream_t stream) {
    const float* x      = (const float*)d_in[0];
    const float* mask   = (const float*)d_in[1];
    const int*   rel    = (const int*)d_in[2];
    const float* qkv_w  = (const float*)d_in[3];
    const float* qkv_b  = (const float*)d_in[4];
    const float* proj_w = (const float*)d_in[5];
    const float* proj_b = (const float*)d_in[6];
    const float* bt     = (const float*)d_in[7];
    float* out = (float*)d_out;

    // ws layout (bytes); total = 313,722,880 (~300 MiB)
    char* ws = (char*)d_ws;
    ushort* qwb  = (ushort*)(ws);                  // 768*256 bf16   (393216 B)
    ushort* pwb  = (ushort*)(ws + 393216);         // 256*256 bf16   (131072 B)
    float*  comb = (float*) (ws + 524288);         // 64*8*2401 f32  (4917248 B)
    ushort* qws  = (ushort*)(ws + 5441536);        // 32768*49*32 bf16
    ushort* kws  = (ushort*)(ws + 108201984);
    ushort* vws  = (ushort*)(ws + 210962432);
    (void)ws_size; (void)in_sizes; (void)n_in; (void)out_size;

    k_cvt_w<<<dim3(1024), dim3(256), 0, stream>>>(qkv_w, proj_w, qwb, pwb);
    k_comb <<<dim3(512),  dim3(256), 0, stream>>>(mask, rel, bt, comb);
    k_qkv  <<<dim3(9408), dim3(256), 0, stream>>>(x, qwb, qkv_b, qws, kws, vws);
    k_attn_proj<<<dim3(4096), dim3(512), 0, stream>>>(qws, kws, vws, comb, pwb,
                                                      proj_b, out);
}

// Round 3
// 504.589 us; speedup vs baseline: 1.0940x; 1.0940x over previous
//
#include <hip/hip_runtime.h>
#include <cstdint>

// ---------------------------------------------------------------------------
// WindowAttention (Swin): B_WIN=4096 windows, N=49 tokens, DIM=256, HEADS=8,
// head_dim=32, NW=64 masks.
// Pipeline: cvt_w -> comb(padded 64-stride) -> qkv gemm (reg-staged fp32 A,
// r1 bf16 LDS frag path, XCD mapping) -> fused attention+proj (swapped QK^T,
// in-lane softmax, pre-normalized P).
// ---------------------------------------------------------------------------

typedef __attribute__((ext_vector_type(8))) short short8;   // bf16x8 frag
typedef __attribute__((ext_vector_type(4))) float floatx4;  // fp32x4 acc frag

__device__ __forceinline__ ushort f2bf(float f) {
    uint32_t u = __float_as_uint(f);
    u += 0x7FFFu + ((u >> 16) & 1u);   // RNE
    return (ushort)(u >> 16);
}

__device__ __forceinline__ uint32_t cvtpk(float lo, float hi) {
    uint32_t r;
    asm("v_cvt_pk_bf16_f32 %0, %1, %2" : "=v"(r) : "v"(lo), "v"(hi));
    return r;
}

__device__ __forceinline__ void gl_lds16(const void* g, void* lds) {
    __builtin_amdgcn_global_load_lds(
        (const __attribute__((address_space(1))) uint32_t*)g,
        (__attribute__((address_space(3))) uint32_t*)lds, 16, 0, 0);
}

// ---------------------------------------------------------------- kernel 0b
__global__ __launch_bounds__(256) void k_cvt_w(const float* __restrict__ qw,
                                               const float* __restrict__ pw,
                                               ushort* __restrict__ qwb,
                                               ushort* __restrict__ pwb) {
    int i = blockIdx.x * 256 + threadIdx.x;
    if (i < 196608) qwb[i] = f2bf(qw[i]);
    else            pwb[i - 196608] = f2bf(pw[i - 196608]);
}

// ---------------------------------------------------------------- kernel 0c
// comb[wh][n][m] padded to stride 64: comb[wh*4096 + n*64 + m], m-pad zeroed.
__global__ __launch_bounds__(256) void k_comb(const float* __restrict__ mask,
                                              const int* __restrict__ rel,
                                              const float* __restrict__ bt,
                                              float* __restrict__ comb) {
    const int wh = blockIdx.x;
    const int w = wh >> 3, h = wh & 7;
    const float* mw = mask + (size_t)w * 2401;
    float* out = comb + (size_t)wh * 4096;
    for (int e = threadIdx.x; e < 49 * 64; e += 256) {
        const int n = e >> 6, m = e & 63;
        out[e] = (m < 49) ? mw[n * 49 + m] + bt[rel[n * 49 + m] * 8 + h] : 0.0f;
    }
}

// ---------------------------------------------------------------- kernel 1
// qkv gemm: C[tok][c] = sum_k x[tok][k]*qkv_w[c][k] + qkv_b[c]
// M=200704, N=768, K=256. BM=BN=128, BK=32.
// A: fp32 x -> regs (prefetch kt+1 under MFMA) -> cvtpk -> bf16 LDS (r1 layout).
// B: bf16 via global_load_lds (r1 layout). XCD-contiguous block mapping.
__global__ __launch_bounds__(256) void k_qkv(const float* __restrict__ x,
                                             const ushort* __restrict__ wb,
                                             const float* __restrict__ qb,
                                             ushort* __restrict__ qws,
                                             ushort* __restrict__ kws,
                                             ushort* __restrict__ vws) {
    __shared__ ushort As[128 * 32];   // 8 KB
    __shared__ ushort Bs[128 * 32];   // 8 KB
    const int bid = blockIdx.x;
    const int gid = (bid & 7) * 1176 + (bid >> 3);   // bijective, 9408 = 8*1176
    const int bn = gid % 6, bm = gid / 6;            // 1176 % 6 == 0: no split
    const int t = threadIdx.x;
    const int l = t & 63, w = t >> 6;
    const int wm = w >> 1, wn = w & 1;

    // A staging assignment: thread t handles row r, 16-col half hh
    const int ar = t >> 1, hh = (t & 1) * 16;
    const float* Axg = x + (size_t)(bm * 128 + ar) * 256 + hh;

    // B staging (r1 pattern)
    const int srow = t >> 2, scol = (t & 3) * 8;
    const ushort* Bg = wb + (size_t)bn * 128 * 256;

    const floatx4 zf = {0.f, 0.f, 0.f, 0.f};
    floatx4 acc[4][4];
#pragma unroll
    for (int i = 0; i < 4; ++i)
#pragma unroll
        for (int j = 0; j < 4; ++j) acc[i][j] = zf;

    const int aoff = (wm * 64 + (l & 15)) * 32 + (l >> 4) * 8;
    const int boff = (wn * 64 + (l & 15)) * 32 + (l >> 4) * 8;

    float4 pre[4];
#pragma unroll
    for (int i = 0; i < 4; ++i) pre[i] = *(const float4*)(Axg + i * 4);

    for (int kt = 0; kt < 8; ++kt) {
        // convert prefetched A and write bf16 to LDS
        uint4 wa, wb4;
        wa.x = cvtpk(pre[0].x, pre[0].y); wa.y = cvtpk(pre[0].z, pre[0].w);
        wa.z = cvtpk(pre[1].x, pre[1].y); wa.w = cvtpk(pre[1].z, pre[1].w);
        wb4.x = cvtpk(pre[2].x, pre[2].y); wb4.y = cvtpk(pre[2].z, pre[2].w);
        wb4.z = cvtpk(pre[3].x, pre[3].y); wb4.w = cvtpk(pre[3].z, pre[3].w);
        *(uint4*)(As + ar * 32 + hh)     = wa;
        *(uint4*)(As + ar * 32 + hh + 8) = wb4;
#pragma unroll
        for (int i = 0; i < 2; ++i)
            gl_lds16(Bg + (size_t)(i * 64 + srow) * 256 + kt * 32 + scol,
                     Bs + i * 2048 + w * 512);
        __syncthreads();
        if (kt < 7) {
#pragma unroll
            for (int i = 0; i < 4; ++i)
                pre[i] = *(const float4*)(Axg + (kt + 1) * 32 + i * 4);
        }
        short8 af[4], bfr[4];
#pragma unroll
        for (int mt = 0; mt < 4; ++mt) af[mt] = *(const short8*)(As + aoff + mt * 512);
#pragma unroll
        for (int nt = 0; nt < 4; ++nt) bfr[nt] = *(const short8*)(Bs + boff + nt * 512);
#pragma unroll
        for (int mt = 0; mt < 4; ++mt)
#pragma unroll
            for (int nt = 0; nt < 4; ++nt)
                acc[mt][nt] = __builtin_amdgcn_mfma_f32_16x16x32_bf16(
                    af[mt], bfr[nt], acc[mt][nt], 0, 0, 0);
        __syncthreads();
    }

#pragma unroll
    for (int nt = 0; nt < 4; ++nt) {
        const int c = bn * 128 + wn * 64 + nt * 16 + (l & 15);
        const int which = c >> 8, hd = (c >> 5) & 7, dd = c & 31;
        const float bias = qb[c];
        ushort* dst = which == 0 ? qws : (which == 1 ? kws : vws);
#pragma unroll
        for (int mt = 0; mt < 4; ++mt)
#pragma unroll
            for (int r = 0; r < 4; ++r) {
                const int tok = bm * 128 + wm * 64 + mt * 16 + (l >> 4) * 4 + r;
                const int b = tok / 49;
                const int n = tok - b * 49;
                dst[(size_t)(b * 8 + hd) * 1568 + n * 32 + dd] =
                    f2bf(acc[mt][nt][r] + bias);
            }
    }
}

// ---------------------------------------------------------------- kernel 2
// Fused attention + output projection. One block (512 thr, 8 waves) per
// window; wave w = head w. Swapped QK^T (S^T in regs): lane li owns query
// n = bq*16+li; keys split over lane groups {li, li+16, li+32, li+48}.
// Softmax in-lane + 2 shfl_xor; P normalized before bf16 pack.
// Per-wave LDS: P[64][72] + vT[32][72] bf16 = 13824 B; ao[64][264] aliased.
__global__ __launch_bounds__(512) void k_attn_proj(
        const ushort* __restrict__ qws, const ushort* __restrict__ kws,
        const ushort* __restrict__ vws, const float* __restrict__ comb,
        const ushort* __restrict__ pwb, const float* __restrict__ pb,
        float* __restrict__ out) {
    __shared__ __align__(16) char smem[8 * 13824];   // 110592 B
    const int w = threadIdx.x >> 6;      // wave id == head
    const int l = threadIdx.x & 63;
    const int b = blockIdx.x;
    const int bh = b * 8 + w;
    const int wdw = b & 63;
    const int g = l >> 4, li = l & 15;

    ushort* P  = (ushort*)(smem + w * 13824);          // [64][72]
    ushort* vT = (ushort*)(smem + w * 13824 + 9216);   // [32][72]
    ushort* ao = (ushort*)smem;                        // [64][264] (aliased)

    const ushort* qg = qws + (size_t)bh * 1568;
    const ushort* kg = kws + (size_t)bh * 1568;
    const ushort* vg = vws + (size_t)bh * 1568;

    // --- Q/K fragments straight from global ---
    const int kq = g * 8;
    const short8 z8 = {0, 0, 0, 0, 0, 0, 0, 0};
    short8 qf[4], kf[4];
#pragma unroll
    for (int mt = 0; mt < 4; ++mt) {
        const int n = mt * 16 + li;
        qf[mt] = (n < 49) ? *(const short8*)(qg + n * 32 + kq) : z8;
        kf[mt] = (n < 49) ? *(const short8*)(kg + n * 32 + kq) : z8;
    }

    // --- stage V transposed into LDS: vT[dd][m] ---
    uint4 vv[4];
    if (l < 49) {
#pragma unroll
        for (int i = 0; i < 4; ++i) vv[i] = *(const uint4*)(vg + (size_t)l * 32 + i * 8);
    } else {
#pragma unroll
        for (int i = 0; i < 4; ++i) vv[i] = make_uint4(0u, 0u, 0u, 0u);
    }
#pragma unroll
    for (int i = 0; i < 4; ++i) {
        const uint32_t uu[4] = {vv[i].x, vv[i].y, vv[i].z, vv[i].w};
#pragma unroll
        for (int j = 0; j < 4; ++j) {
            const int dd = i * 8 + j * 2;
            vT[dd * 72 + l]       = (ushort)(uu[j] & 0xFFFFu);
            vT[(dd + 1) * 72 + l] = (ushort)(uu[j] >> 16);
        }
    }

    // --- S^T = K Q^T : sac[bq][ak][r] = S[n=bq*16+li][m=ak*16+g*4+r] ---
    const floatx4 zf = {0.f, 0.f, 0.f, 0.f};
    floatx4 sac[4][4];
#pragma unroll
    for (int bq = 0; bq < 4; ++bq)
#pragma unroll
        for (int ak = 0; ak < 4; ++ak)
            sac[bq][ak] = __builtin_amdgcn_mfma_f32_16x16x32_bf16(kf[ak], qf[bq], zf, 0, 0, 0);

    const float* cw = comb + (size_t)(wdw * 8 + w) * 4096;
    const float scale = 0.17677669529663687f;  // 32^-0.5

    // --- in-lane softmax per query tile bq; write normalized bf16 P ---
#pragma unroll
    for (int bq = 0; bq < 4; ++bq) {
        const int n = bq * 16 + li;
        const float* cr = cw + n * 64 + g * 4;
        float4 c0 = *(const float4*)(cr);
        float4 c1 = *(const float4*)(cr + 16);
        float4 c2 = *(const float4*)(cr + 32);
        const float c3x = cr[48];
        float v[12];
        v[0]  = sac[bq][0][0] * scale + c0.x;
        v[1]  = sac[bq][0][1] * scale + c0.y;
        v[2]  = sac[bq][0][2] * scale + c0.z;
        v[3]  = sac[bq][0][3] * scale + c0.w;
        v[4]  = sac[bq][1][0] * scale + c1.x;
        v[5]  = sac[bq][1][1] * scale + c1.y;
        v[6]  = sac[bq][1][2] * scale + c1.z;
        v[7]  = sac[bq][1][3] * scale + c1.w;
        v[8]  = sac[bq][2][0] * scale + c2.x;
        v[9]  = sac[bq][2][1] * scale + c2.y;
        v[10] = sac[bq][2][2] * scale + c2.z;
        v[11] = sac[bq][2][3] * scale + c2.w;
        // key 48 lives only on g==0, r==0
        const float v48 = (g == 0) ? sac[bq][3][0] * scale + c3x : -3.0e38f;
        float mx = fmaxf(fmaxf(fmaxf(v[0], v[1]), fmaxf(v[2], v[3])),
                         fmaxf(fmaxf(v[4], v[5]), fmaxf(v[6], v[7])));
        mx = fmaxf(mx, fmaxf(fmaxf(v[8], v[9]), fmaxf(v[10], v[11])));
        mx = fmaxf(mx, v48);
        mx = fmaxf(mx, __shfl_xor(mx, 16, 64));
        mx = fmaxf(mx, __shfl_xor(mx, 32, 64));
        float e[12], s = 0.f;
#pragma unroll
        for (int i = 0; i < 12; ++i) { e[i] = __expf(v[i] - mx); s += e[i]; }
        const float e48 = __expf(v48 - mx);   // ==0 for g>0 (underflow)
        s += e48;
        s += __shfl_xor(s, 16, 64);
        s += __shfl_xor(s, 32, 64);
        const float inv = 1.0f / s;
        // pack normalized P and write: dwords a*8+g*2 (+1) of row n
        uint2 pk;
#pragma unroll
        for (int a = 0; a < 3; ++a) {
            pk.x = cvtpk(e[a * 4 + 0] * inv, e[a * 4 + 1] * inv);
            pk.y = cvtpk(e[a * 4 + 2] * inv, e[a * 4 + 3] * inv);
            *(uint2*)(P + n * 72 + a * 16 + g * 4) = pk;
        }
        pk.x = cvtpk(e48 * inv, 0.f);
        pk.y = 0u;
        *(uint2*)(P + n * 72 + 48 + g * 4) = pk;
    }

    // --- O = P V (wave-internal LDS, in-order: no barrier needed) ---
    floatx4 oac[4][2];
#pragma unroll
    for (int mt = 0; mt < 4; ++mt)
#pragma unroll
        for (int nt = 0; nt < 2; ++nt) oac[mt][nt] = zf;
#pragma unroll
    for (int ks = 0; ks < 2; ++ks) {
        short8 vf[2];
#pragma unroll
        for (int nt = 0; nt < 2; ++nt) {
            const int dd = nt * 16 + li;
            vf[nt] = *(const short8*)(vT + dd * 72 + ks * 32 + g * 8);
        }
#pragma unroll
        for (int mt = 0; mt < 4; ++mt) {
            const int n = mt * 16 + li;
            const short8 pf = *(const short8*)(P + n * 72 + ks * 32 + g * 8);
#pragma unroll
            for (int nt = 0; nt < 2; ++nt)
                oac[mt][nt] = __builtin_amdgcn_mfma_f32_16x16x32_bf16(pf, vf[nt], oac[mt][nt], 0, 0, 0);
        }
    }

    __syncthreads();   // all waves done with P/vT; safe to alias with ao

    // --- store O (already normalized) into ao[n][w*32+dd]; zero rows 49..63
#pragma unroll
    for (int mt = 0; mt < 4; ++mt)
#pragma unroll
        for (int rr = 0; rr < 4; ++rr) {
            const int n = mt * 16 + g * 4 + rr;
            if (n < 49) {
#pragma unroll
                for (int nt = 0; nt < 2; ++nt) {
                    const int dd = nt * 16 + li;
                    ao[n * 264 + w * 32 + dd] = f2bf(oac[mt][nt][rr]);
                }
            }
        }
    for (int idx = l; idx < 15 * 16; idx += 64) {
        const int n = 49 + (idx >> 4);
        const int du = idx & 15;
        *(uint32_t*)(ao + n * 264 + w * 32 + du * 2) = 0u;
    }
    __syncthreads();

    // --- proj: out[n][c] = sum_k ao[n][k] * proj_w[c][k] + proj_b[c] ---
    floatx4 pacc[4][2];
#pragma unroll
    for (int mt = 0; mt < 4; ++mt)
#pragma unroll
        for (int nt = 0; nt < 2; ++nt) pacc[mt][nt] = zf;
#pragma unroll
    for (int kt = 0; kt < 8; ++kt) {
        short8 afr[4], wfr[2];
#pragma unroll
        for (int mt = 0; mt < 4; ++mt)
            afr[mt] = *(const short8*)(ao + (mt * 16 + li) * 264 + kt * 32 + g * 8);
#pragma unroll
        for (int nt = 0; nt < 2; ++nt)
            wfr[nt] = *(const short8*)(pwb + (size_t)(w * 32 + nt * 16 + li) * 256 + kt * 32 + g * 8);
#pragma unroll
        for (int mt = 0; mt < 4; ++mt)
#pragma unroll
            for (int nt = 0; nt < 2; ++nt)
                pacc[mt][nt] = __builtin_amdgcn_mfma_f32_16x16x32_bf16(
                    afr[mt], wfr[nt], pacc[mt][nt], 0, 0, 0);
    }

    float* og = out + (size_t)b * 49 * 256;
#pragma unroll
    for (int nt = 0; nt < 2; ++nt) {
        const int c = w * 32 + nt * 16 + li;
        const float bias = pb[c];
#pragma unroll
        for (int mt = 0; mt < 4; ++mt)
#pragma unroll
            for (int r = 0; r < 4; ++r) {
                const int n = mt * 16 + g * 4 + r;
                if (n < 49) og[(size_t)n * 256 + c] = pacc[mt][nt][r] + bias;
            }
    }
}

// ---------------------------------------------------------------------------
extern "C" void kernel_launch(void* const* d_in, const int* in_sizes, int n_in,
                              void* d_out, int out_size, void* d_ws, size_t ws_size,
                              hipStream_t stream) {
    const float* x      = (const float*)d_in[0];
    const float* mask   = (const float*)d_in[1];
    const int*   rel    = (const int*)d_in[2];
    const float* qkv_w  = (const float*)d_in[3];
    const float* qkv_b  = (const float*)d_in[4];
    const float* proj_w = (const float*)d_in[5];
    const float* proj_b = (const float*)d_in[6];
    const float* bt     = (const float*)d_in[7];
    float* out = (float*)d_out;

    // ws layout (bytes); total = 317,194,240 (~303 MiB)
    char* ws = (char*)d_ws;
    ushort* qwb  = (ushort*)(ws);                  // 768*256 bf16   (393216 B)
    ushort* pwb  = (ushort*)(ws + 393216);         // 256*256 bf16   (131072 B)
    float*  comb = (float*) (ws + 524288);         // 512*64*64 f32  (8388608 B)
    ushort* qws  = (ushort*)(ws + 8912896);        // 32768*49*32 bf16
    ushort* kws  = (ushort*)(ws + 111673344);
    ushort* vws  = (ushort*)(ws + 214433792);
    (void)ws_size; (void)in_sizes; (void)n_in; (void)out_size;

    k_cvt_w<<<dim3(1024), dim3(256), 0, stream>>>(qkv_w, proj_w, qwb, pwb);
    k_comb <<<dim3(512),  dim3(256), 0, stream>>>(mask, rel, bt, comb);
    k_qkv  <<<dim3(9408), dim3(256), 0, stream>>>(x, qwb, qkv_b, qws, kws, vws);
    k_attn_proj<<<dim3(4096), dim3(512), 0, stream>>>(qws, kws, vws, comb, pwb,
                                                      proj_b, out);
}

// Round 5
// 500.529 us; speedup vs baseline: 1.1029x; 1.0081x over previous
//
#include <hip/hip_runtime.h>
#include <cstdint>

// ---------------------------------------------------------------------------
// WindowAttention (Swin): B_WIN=4096 windows, N=49 tokens, DIM=256, HEADS=8,
// head_dim=32, NW=64 masks.
// S4 = proven components: S0 qkv gemm (+XCD remap, +V-transposed epilogue),
// S2 fused attention+proj (V read from transposed global, pad-masked in regs,
// 2 blocks/CU).
// ---------------------------------------------------------------------------

typedef __attribute__((ext_vector_type(8))) short short8;   // bf16x8 frag
typedef __attribute__((ext_vector_type(4))) float floatx4;  // fp32x4 acc frag

__device__ __forceinline__ ushort f2bf(float f) {
    uint32_t u = __float_as_uint(f);
    u += 0x7FFFu + ((u >> 16) & 1u);   // RNE
    return (ushort)(u >> 16);
}

__device__ __forceinline__ uint32_t cvtpk(float lo, float hi) {
    uint32_t r;
    asm("v_cvt_pk_bf16_f32 %0, %1, %2" : "=v"(r) : "v"(lo), "v"(hi));
    return r;
}

__device__ __forceinline__ void gl_lds16(const void* g, void* lds) {
    __builtin_amdgcn_global_load_lds(
        (const __attribute__((address_space(1))) uint32_t*)g,
        (__attribute__((address_space(3))) uint32_t*)lds, 16, 0, 0);
}

// ---------------------------------------------------------------- kernel 0a
__global__ __launch_bounds__(256) void k_cvt_x(const float* __restrict__ x,
                                               ushort* __restrict__ xb, int n4) {
    int i = blockIdx.x * blockDim.x + threadIdx.x;
    const int stride = gridDim.x * blockDim.x;
    const float4* x4 = (const float4*)x;
    ushort4* o4 = (ushort4*)xb;
    for (; i < n4; i += stride) {
        float4 v = x4[i];
        ushort4 o;
        o.x = f2bf(v.x); o.y = f2bf(v.y); o.z = f2bf(v.z); o.w = f2bf(v.w);
        o4[i] = o;
    }
}

// ---------------------------------------------------------------- kernel 0b
__global__ __launch_bounds__(256) void k_cvt_w(const float* __restrict__ qw,
                                               const float* __restrict__ pw,
                                               ushort* __restrict__ qwb,
                                               ushort* __restrict__ pwb) {
    int i = blockIdx.x * 256 + threadIdx.x;
    if (i < 196608) qwb[i] = f2bf(qw[i]);
    else            pwb[i - 196608] = f2bf(pw[i - 196608]);
}

// ---------------------------------------------------------------- kernel 0c
// comb[wh][n][m] padded to stride 64: comb[wh*4096 + n*64 + m], m-pad zeroed.
__global__ __launch_bounds__(256) void k_comb(const float* __restrict__ mask,
                                              const int* __restrict__ rel,
                                              const float* __restrict__ bt,
                                              float* __restrict__ comb) {
    const int wh = blockIdx.x;
    const int w = wh >> 3, h = wh & 7;
    const float* mw = mask + (size_t)w * 2401;
    float* out = comb + (size_t)wh * 4096;
    for (int e = threadIdx.x; e < 49 * 64; e += 256) {
        const int n = e >> 6, m = e & 63;
        out[e] = (m < 49) ? mw[n * 49 + m] + bt[rel[n * 49 + m] * 8 + h] : 0.0f;
    }
}

// ---------------------------------------------------------------- kernel 1
// qkv gemm_bt (S0 structure): C[tok][c] = sum_k xb[tok][k]*qkv_w[c][k] + qb[c]
// M=200704, N=768, K=256. BM=BN=128, BK=32. XCD-contiguous block mapping.
// Epilogue: Q/K row-major [bh][n(49)][dd(32)]; V transposed [bh][dd(32)][64].
__global__ __launch_bounds__(256) void k_qkv(const ushort* __restrict__ xb,
                                             const ushort* __restrict__ wb,
                                             const float* __restrict__ qb,
                                             ushort* __restrict__ qws,
                                             ushort* __restrict__ kws,
                                             ushort* __restrict__ vws) {
    __shared__ ushort As[128 * 32];
    __shared__ ushort Bs[128 * 32];
    const int bid = blockIdx.x;
    const int gid = (bid & 7) * 1176 + (bid >> 3);   // bijective, 9408 = 8*1176
    const int bn = gid % 6, bm = gid / 6;            // 1176 % 6 == 0: no split
    const int t = threadIdx.x;
    const int l = t & 63, w = t >> 6;
    const int wm = w >> 1, wn = w & 1;

    const ushort* Ag = xb + (size_t)bm * 128 * 256;
    const ushort* Bg = wb + (size_t)bn * 128 * 256;

    const floatx4 zf = {0.f, 0.f, 0.f, 0.f};
    floatx4 acc[4][4];
#pragma unroll
    for (int i = 0; i < 4; ++i)
#pragma unroll
        for (int j = 0; j < 4; ++j) acc[i][j] = zf;

    const int srow = t >> 2;            // 0..63
    const int scol = (t & 3) * 8;       // 0,8,16,24
    const int aoff = (wm * 64 + (l & 15)) * 32 + (l >> 4) * 8;
    const int boff = (wn * 64 + (l & 15)) * 32 + (l >> 4) * 8;

    for (int kt = 0; kt < 8; ++kt) {
#pragma unroll
        for (int i = 0; i < 2; ++i) {
            gl_lds16(Ag + (size_t)(i * 64 + srow) * 256 + kt * 32 + scol,
                     As + i * 2048 + w * 512);
            gl_lds16(Bg + (size_t)(i * 64 + srow) * 256 + kt * 32 + scol,
                     Bs + i * 2048 + w * 512);
        }
        __syncthreads();
        short8 af[4], bfr[4];
#pragma unroll
        for (int mt = 0; mt < 4; ++mt) af[mt] = *(const short8*)(As + aoff + mt * 512);
#pragma unroll
        for (int nt = 0; nt < 4; ++nt) bfr[nt] = *(const short8*)(Bs + boff + nt * 512);
#pragma unroll
        for (int mt = 0; mt < 4; ++mt)
#pragma unroll
            for (int nt = 0; nt < 4; ++nt)
                acc[mt][nt] = __builtin_amdgcn_mfma_f32_16x16x32_bf16(
                    af[mt], bfr[nt], acc[mt][nt], 0, 0, 0);
        __syncthreads();
    }

#pragma unroll
    for (int nt = 0; nt < 4; ++nt) {
        const int c = bn * 128 + wn * 64 + nt * 16 + (l & 15);
        const int which = c >> 8, hd = (c >> 5) & 7, dd = c & 31;
        const float bias = qb[c];
        if (which < 2) {
            ushort* dst = which == 0 ? qws : kws;
#pragma unroll
            for (int mt = 0; mt < 4; ++mt)
#pragma unroll
                for (int r = 0; r < 4; ++r) {
                    const int tok = bm * 128 + wm * 64 + mt * 16 + (l >> 4) * 4 + r;
                    const int b = tok / 49;
                    const int n = tok - b * 49;
                    dst[(size_t)(b * 8 + hd) * 1568 + n * 32 + dd] =
                        f2bf(acc[mt][nt][r] + bias);
                }
        } else {
#pragma unroll
            for (int mt = 0; mt < 4; ++mt)
#pragma unroll
                for (int r = 0; r < 4; ++r) {
                    const int tok = bm * 128 + wm * 64 + mt * 16 + (l >> 4) * 4 + r;
                    const int b = tok / 49;
                    const int n = tok - b * 49;
                    vws[(size_t)(b * 8 + hd) * 2048 + dd * 64 + n] =
                        f2bf(acc[mt][nt][r] + bias);
                }
        }
    }
}

// ---------------------------------------------------------------- kernel 2
// Fused attention + projection (S2 structure). One block (512 thr) per
// window; wave w = head w. Swapped QK^T (S^T in regs), in-lane softmax,
// pre-normalized P. V fragments read straight from transposed vws; pad keys
// (>=49) masked in registers (NaN-safe). Per-wave LDS: P[64][72] bf16 only
// (9216 B); ao[64][264] aliases the array. Total LDS 73728 B -> 2 blocks/CU.
__global__ __launch_bounds__(512, 4) void k_attn_proj(
        const ushort* __restrict__ qws, const ushort* __restrict__ kws,
        const ushort* __restrict__ vws, const float* __restrict__ comb,
        const ushort* __restrict__ pwb, const float* __restrict__ pb,
        float* __restrict__ out) {
    __shared__ __align__(16) ushort Pa[8][4608];   // per-wave [64][72]
    const int w = threadIdx.x >> 6, l = threadIdx.x & 63;
    const int b = blockIdx.x, bh = b * 8 + w, wdw = b & 63;
    const int g = l >> 4, li = l & 15;
    ushort* P = Pa[w];
    ushort* ao = (ushort*)Pa;                      // [64][264] aliased

    const ushort* qg = qws + (size_t)bh * 1568;
    const ushort* kg = kws + (size_t)bh * 1568;
    const ushort* vg = vws + (size_t)bh * 2048;

    const short8 z8 = {0, 0, 0, 0, 0, 0, 0, 0};
    short8 qf[4], kf[4];
#pragma unroll
    for (int mt = 0; mt < 4; ++mt) {
        const int n = mt * 16 + li;
        qf[mt] = (n < 49) ? *(const short8*)(qg + n * 32 + g * 8) : z8;
        kf[mt] = (n < 49) ? *(const short8*)(kg + n * 32 + g * 8) : z8;
    }

    // V fragments from transposed global: vg[dd][key], dd = nt*16+li,
    // key = ks*32 + g*8 + j. Mask pad keys >= 49 (NaN-safe: memory ignored).
    short8 vf[2][2];
#pragma unroll
    for (int ks = 0; ks < 2; ++ks)
#pragma unroll
        for (int nt = 0; nt < 2; ++nt)
            vf[ks][nt] = *(const short8*)(vg + (nt * 16 + li) * 64 + ks * 32 + g * 8);
#pragma unroll
    for (int nt = 0; nt < 2; ++nt) {
        if (g == 2) {            // keys 48..55: keep only key 48 (j==0)
            short8 m = z8;
            m[0] = vf[1][nt][0];
            vf[1][nt] = m;
        } else if (g == 3) {     // keys 56..63: all pad
            vf[1][nt] = z8;
        }
    }

    // --- S^T = K Q^T : sac[bq][ak][r] = S[n=bq*16+li][m=ak*16+g*4+r] ---
    const floatx4 zf = {0.f, 0.f, 0.f, 0.f};
    floatx4 sac[4][4];
#pragma unroll
    for (int bq = 0; bq < 4; ++bq)
#pragma unroll
        for (int ak = 0; ak < 4; ++ak)
            sac[bq][ak] = __builtin_amdgcn_mfma_f32_16x16x32_bf16(kf[ak], qf[bq], zf, 0, 0, 0);

    const float* cw = comb + (size_t)(wdw * 8 + w) * 4096;
    const float scale = 0.17677669529663687f;  // 32^-0.5

    // --- in-lane softmax per query tile bq; write normalized bf16 P ---
#pragma unroll
    for (int bq = 0; bq < 4; ++bq) {
        const int n = bq * 16 + li;
        const float* cr = cw + n * 64 + g * 4;
        const float4 c0 = *(const float4*)(cr);
        const float4 c1 = *(const float4*)(cr + 16);
        const float4 c2 = *(const float4*)(cr + 32);
        const float c3x = cr[48];
        float v[12];
        v[0]  = sac[bq][0][0] * scale + c0.x;
        v[1]  = sac[bq][0][1] * scale + c0.y;
        v[2]  = sac[bq][0][2] * scale + c0.z;
        v[3]  = sac[bq][0][3] * scale + c0.w;
        v[4]  = sac[bq][1][0] * scale + c1.x;
        v[5]  = sac[bq][1][1] * scale + c1.y;
        v[6]  = sac[bq][1][2] * scale + c1.z;
        v[7]  = sac[bq][1][3] * scale + c1.w;
        v[8]  = sac[bq][2][0] * scale + c2.x;
        v[9]  = sac[bq][2][1] * scale + c2.y;
        v[10] = sac[bq][2][2] * scale + c2.z;
        v[11] = sac[bq][2][3] * scale + c2.w;
        // key 48 lives only on g==0, r==0
        const float v48 = (g == 0) ? sac[bq][3][0] * scale + c3x : -3.0e38f;
        float mx = fmaxf(fmaxf(fmaxf(v[0], v[1]), fmaxf(v[2], v[3])),
                         fmaxf(fmaxf(v[4], v[5]), fmaxf(v[6], v[7])));
        mx = fmaxf(mx, fmaxf(fmaxf(v[8], v[9]), fmaxf(v[10], v[11])));
        mx = fmaxf(mx, v48);
        mx = fmaxf(mx, __shfl_xor(mx, 16, 64));
        mx = fmaxf(mx, __shfl_xor(mx, 32, 64));
        float e[12], s = 0.f;
#pragma unroll
        for (int i = 0; i < 12; ++i) { e[i] = __expf(v[i] - mx); s += e[i]; }
        const float e48 = __expf(v48 - mx);   // exactly 0 for g>0
        s += e48;
        s += __shfl_xor(s, 16, 64);
        s += __shfl_xor(s, 32, 64);
        const float inv = 1.0f / s;
        uint2 pk;
#pragma unroll
        for (int a = 0; a < 3; ++a) {
            pk.x = cvtpk(e[a * 4 + 0] * inv, e[a * 4 + 1] * inv);
            pk.y = cvtpk(e[a * 4 + 2] * inv, e[a * 4 + 3] * inv);
            *(uint2*)(P + n * 72 + a * 16 + g * 4) = pk;
        }
        pk.x = cvtpk(e48 * inv, 0.f);
        pk.y = 0u;
        *(uint2*)(P + n * 72 + 48 + g * 4) = pk;   // cols 49..63 exact 0
    }

    // --- O = P V (wave-internal LDS, in-order: no barrier needed) ---
    floatx4 oac[4][2];
#pragma unroll
    for (int mt = 0; mt < 4; ++mt)
#pragma unroll
        for (int nt = 0; nt < 2; ++nt) oac[mt][nt] = zf;
#pragma unroll
    for (int ks = 0; ks < 2; ++ks)
#pragma unroll
        for (int mt = 0; mt < 4; ++mt) {
            const short8 pf = *(const short8*)(P + (mt * 16 + li) * 72 + ks * 32 + g * 8);
            oac[mt][0] = __builtin_amdgcn_mfma_f32_16x16x32_bf16(pf, vf[ks][0], oac[mt][0], 0, 0, 0);
            oac[mt][1] = __builtin_amdgcn_mfma_f32_16x16x32_bf16(pf, vf[ks][1], oac[mt][1], 0, 0, 0);
        }

    __syncthreads();   // all waves done with P; safe to alias with ao

    // --- store O (normalized) into ao[n][w*32+dd]; zero rows 49..63 ---
#pragma unroll
    for (int mt = 0; mt < 4; ++mt)
#pragma unroll
        for (int rr = 0; rr < 4; ++rr) {
            const int n = mt * 16 + g * 4 + rr;
            if (n < 49) {
#pragma unroll
                for (int nt = 0; nt < 2; ++nt)
                    ao[n * 264 + w * 32 + nt * 16 + li] = f2bf(oac[mt][nt][rr]);
            }
        }
    for (int idx = l; idx < 240; idx += 64) {
        const int n = 49 + (idx >> 4);
        const int du = idx & 15;
        *(uint32_t*)(ao + n * 264 + w * 32 + du * 2) = 0u;
    }
    __syncthreads();

    // --- proj: out[n][c] = sum_k ao[n][k] * proj_w[c][k] + proj_b[c] ---
    floatx4 pacc[4][2];
#pragma unroll
    for (int mt = 0; mt < 4; ++mt)
#pragma unroll
        for (int nt = 0; nt < 2; ++nt) pacc[mt][nt] = zf;
#pragma unroll
    for (int kt = 0; kt < 8; ++kt) {
        short8 afr[4], wfr[2];
#pragma unroll
        for (int mt = 0; mt < 4; ++mt)
            afr[mt] = *(const short8*)(ao + (mt * 16 + li) * 264 + kt * 32 + g * 8);
#pragma unroll
        for (int nt = 0; nt < 2; ++nt)
            wfr[nt] = *(const short8*)(pwb + (size_t)(w * 32 + nt * 16 + li) * 256 + kt * 32 + g * 8);
#pragma unroll
        for (int mt = 0; mt < 4; ++mt)
#pragma unroll
            for (int nt = 0; nt < 2; ++nt)
                pacc[mt][nt] = __builtin_amdgcn_mfma_f32_16x16x32_bf16(
                    afr[mt], wfr[nt], pacc[mt][nt], 0, 0, 0);
    }

    float* og = out + (size_t)b * 49 * 256;
#pragma unroll
    for (int nt = 0; nt < 2; ++nt) {
        const int c = w * 32 + nt * 16 + li;
        const float bias = pb[c];
#pragma unroll
        for (int mt = 0; mt < 4; ++mt)
#pragma unroll
            for (int r = 0; r < 4; ++r) {
                const int n = mt * 16 + g * 4 + r;
                if (n < 49) og[(size_t)n * 256 + c] = pacc[mt][nt][r] + bias;
            }
    }
}

// ---------------------------------------------------------------------------
extern "C" void kernel_launch(void* const* d_in, const int* in_sizes, int n_in,
                              void* d_out, int out_size, void* d_ws, size_t ws_size,
                              hipStream_t stream) {
    const float* x      = (const float*)d_in[0];
    const float* mask   = (const float*)d_in[1];
    const int*   rel    = (const int*)d_in[2];
    const float* qkv_w  = (const float*)d_in[3];
    const float* qkv_b  = (const float*)d_in[4];
    const float* proj_w = (const float*)d_in[5];
    const float* proj_b = (const float*)d_in[6];
    const float* bt     = (const float*)d_in[7];
    float* out = (float*)d_out;

    // ws layout (bytes); total = 451,411,968 (~431 MiB; S0 proved >=495 MiB ok)
    char* ws = (char*)d_ws;
    ushort* qwb  = (ushort*)(ws);                  // 768*256 bf16   (393216 B)
    ushort* pwb  = (ushort*)(ws + 393216);         // 256*256 bf16   (131072 B)
    float*  comb = (float*) (ws + 524288);         // 512*64*64 f32  (8388608 B)
    ushort* xb   = (ushort*)(ws + 8912896);        // 200704*256 bf16
    ushort* qws  = (ushort*)(ws + 111673344);      // 32768*49*32 bf16
    ushort* kws  = (ushort*)(ws + 214433792);      // 32768*49*32 bf16
    ushort* vws  = (ushort*)(ws + 317194240);      // 32768*32*64 bf16 (transposed)
    (void)ws_size; (void)in_sizes; (void)n_in; (void)out_size;

    k_cvt_x<<<dim3(2048), dim3(256), 0, stream>>>(x, xb, 12845056);
    k_cvt_w<<<dim3(1024), dim3(256), 0, stream>>>(qkv_w, proj_w, qwb, pwb);
    k_comb <<<dim3(512),  dim3(256), 0, stream>>>(mask, rel, bt, comb);
    k_qkv  <<<dim3(9408), dim3(256), 0, stream>>>(xb, qwb, qkv_b, qws, kws, vws);
    k_attn_proj<<<dim3(4096), dim3(512), 0, stream>>>(qws, kws, vws, comb, pwb,
                                                      proj_b, out);
}